// Round 4
// baseline (234.055 us; speedup 1.0000x reference)
//
#include <hip/hip_runtime.h>
#include <hip/hip_bf16.h>

#define B_ 2
#define C_ 512
#define H_ 50
#define W_ 75
#define N_ 2000
#define SS (1.0f/16.0f)

#define SB (H_ * W_ * C_)   // batch stride (elements), NHWC
#define SH (W_ * C_)        // row stride
#define SW (C_)             // col stride

// lgkm-only barrier: orders LDS traffic across the workgroup WITHOUT
// draining global loads/stores (HIP __syncthreads emits vmcnt(0), forcing a
// block-wide wait for all outstanding HBM stores every chunk).
#define BAR_LGKM() asm volatile("s_waitcnt lgkmcnt(0)\n\ts_barrier" ::: "memory")

__device__ __forceinline__ float bf2f(unsigned short u) {
    union { unsigned i; float f; } c; c.i = (unsigned)u << 16; return c.f;
}

// fused transpose+convert: (B,C,H,W) fp32 -> (B,H,W,C) bf16
__global__ __launch_bounds__(256) void transcvt_k(const float* __restrict__ in,
                                                  __hip_bfloat16* __restrict__ out) {
    __shared__ float tile[32][33];
    const int b   = blockIdx.z;
    const int hw0 = blockIdx.x * 32;
    const int c0  = blockIdx.y * 32;
    const int tx  = threadIdx.x;
    const int ty  = threadIdx.y;
    #pragma unroll
    for (int r = 0; r < 32; r += 8) {
        int c  = c0 + ty + r;
        int hw = hw0 + tx;
        if (c < C_ && hw < H_ * W_)
            tile[ty + r][tx] = in[(b * C_ + c) * (H_ * W_) + hw];
    }
    __syncthreads();
    #pragma unroll
    for (int r = 0; r < 32; r += 8) {
        int hw = hw0 + ty + r;
        int c  = c0 + tx;
        if (hw < H_ * W_ && c < C_)
            out[(b * (H_ * W_) + hw) * C_ + c] = __float2bfloat16(tile[tx][ty + r]);
    }
}

// v6 = v4 structure (single sval buffer, 8 blocks/CU) +
//  - NON-TEMPORAL output stores: stream 200.7MB past L2 so the per-chunk
//    feature slice (~1.9MB) stays L2-resident for the gather (the theory:
//    write-allocate store traffic was evicting it -> gather fell to L3,
//    insensitive to LDS/barrier/occupancy changes as observed v4/v5).
//  - lgkm-only barriers in the chunk loop (no per-chunk vmcnt(0) drain).
// sval channel-major stride 65: write 2-way banks (free), read stride-1.
__global__ __launch_bounds__(256) void roi_avg_v6(
    const __hip_bfloat16* __restrict__ ftb, const float* __restrict__ rois,
    float* __restrict__ out)
{
    __shared__ float  sval[64 * 65];   // [chan-in-chunk][sample], stride 65
    __shared__ float4 swt[64];
    __shared__ int    soff[64];

    const int n   = blockIdx.x;
    const int tid = threadIdx.x;

    if (tid < 64) {
        const int s = tid;
        const int j = s >> 3;
        const int i = s & 7;
        const float bfv = rois[n * 5 + 0];
        const float x1 = rois[n * 5 + 1] * SS;
        const float y1 = rois[n * 5 + 2] * SS;
        const float x2 = rois[n * 5 + 3] * SS;
        const float y2 = rois[n * 5 + 4] * SS;
        const int b = (int)bfv;
        const float roi_w = fmaxf(x2 - x1 + 1.0f, 0.0f);
        const float roi_h = fmaxf(y2 - y1 + 1.0f, 0.0f);
        const float h = y1 + (float)j * (roi_h / 7.0f);
        const float w = x1 + (float)i * (roi_w / 7.0f);
        const bool valid = (h >= 0.0f) && (h < (float)H_) &&
                           (w >= 0.0f) && (w < (float)W_);
        int hs = (int)floorf(h); hs = hs < 0 ? 0 : (hs > H_ - 2 ? H_ - 2 : hs);
        int ws = (int)floorf(w); ws = ws < 0 ? 0 : (ws > W_ - 2 ? W_ - 2 : ws);
        const float hr = h - (float)hs;
        const float wr = w - (float)ws;
        const float vz = valid ? 1.0f : 0.0f;
        float4 wt;
        wt.x = (1.0f - hr) * (1.0f - wr) * vz;
        wt.y = (1.0f - hr) * wr * vz;
        wt.z = hr * (1.0f - wr) * vz;
        wt.w = hr * wr * vz;
        swt[s]  = wt;
        soff[s] = b * SB + hs * SH + ws * SW;
    }
    __syncthreads();

    const unsigned short* const ft = (const unsigned short*)ftb;
    const int lane = tid & 63;
    const int wv   = tid >> 6;
    const int q    = lane >> 4;        // sample sub-index 0..3
    const int l    = lane & 15;        // channel-quad index
    const int cl   = l * 4;            // channel within chunk (0..63)

    for (int chunk = 0; chunk < 8; ++chunk) {
        const int cbase = chunk * 64 + cl;
        #pragma unroll
        for (int k = 0; k < 4; ++k) {
            const int s = wv * 16 + k * 4 + q;
            const float4 wt = swt[s];
            const unsigned short* p = ft + soff[s] + cbase;
            const ushort4 a = *(const ushort4*)(p);
            const ushort4 bq = *(const ushort4*)(p + SW);
            const ushort4 c = *(const ushort4*)(p + SH);
            const ushort4 d = *(const ushort4*)(p + SH + SW);
            const float v0 = bf2f(a.x) * wt.x + bf2f(bq.x) * wt.y + bf2f(c.x) * wt.z + bf2f(d.x) * wt.w;
            const float v1 = bf2f(a.y) * wt.x + bf2f(bq.y) * wt.y + bf2f(c.y) * wt.z + bf2f(d.y) * wt.w;
            const float v2 = bf2f(a.z) * wt.x + bf2f(bq.z) * wt.y + bf2f(c.z) * wt.z + bf2f(d.z) * wt.w;
            const float v3 = bf2f(a.w) * wt.x + bf2f(bq.w) * wt.y + bf2f(c.w) * wt.z + bf2f(d.w) * wt.w;
            // channel-major scatter; stride 65 dwords -> 2x ds_write2_b32
            sval[(cl + 0) * 65 + s] = v0;
            sval[(cl + 1) * 65 + s] = v1;
            sval[(cl + 2) * 65 + s] = v2;
            sval[(cl + 3) * 65 + s] = v3;
        }
        BAR_LGKM();
        const int out_base = n * (C_ * 49) + chunk * (64 * 49);
        #pragma unroll
        for (int r = 0; r < 13; ++r) {
            const int o = r * 256 + tid;
            if (o < 64 * 49) {
                const int c  = o / 49;       // chan-in-chunk, ~fixed across a wave
                const int ji = o - c * 49;
                const int jj = ji / 7;
                const int s  = ji + jj;      // j*8+i == (j*7+i)+j
                const float* sv = &sval[c * 65 + s];
                // (sv[0],sv[1]) and (sv[8],sv[9]) -> 2x ds_read2_b32, s-stride-1
                const float v = 0.25f * (sv[0] + sv[1] + sv[8] + sv[9]);
                __builtin_nontemporal_store(v, &out[out_base + o]);  // stream past L2
            }
        }
        BAR_LGKM();
    }
}

// Fallback: fp32 native-layout version (only if ws too small)
__global__ __launch_bounds__(256) void roi_avg_generic(
    const float* __restrict__ ft, const float* __restrict__ rois,
    float* __restrict__ out, int sB, int sH, int sW, int sC)
{
    __shared__ float  sval[64 * 65];
    __shared__ float4 swt[64];
    __shared__ int    soff[64];
    const int n   = blockIdx.x;
    const int tid = threadIdx.x;
    if (tid < 64) {
        const int s = tid;
        const int j = s >> 3;
        const int i = s & 7;
        const float bfv = rois[n * 5 + 0];
        const float x1 = rois[n * 5 + 1] * SS;
        const float y1 = rois[n * 5 + 2] * SS;
        const float x2 = rois[n * 5 + 3] * SS;
        const float y2 = rois[n * 5 + 4] * SS;
        const int b = (int)bfv;
        const float roi_w = fmaxf(x2 - x1 + 1.0f, 0.0f);
        const float roi_h = fmaxf(y2 - y1 + 1.0f, 0.0f);
        const float h = y1 + (float)j * (roi_h / 7.0f);
        const float w = x1 + (float)i * (roi_w / 7.0f);
        const bool valid = (h >= 0.0f) && (h < (float)H_) && (w >= 0.0f) && (w < (float)W_);
        int hs = (int)floorf(h); hs = hs < 0 ? 0 : (hs > H_ - 2 ? H_ - 2 : hs);
        int ws = (int)floorf(w); ws = ws < 0 ? 0 : (ws > W_ - 2 ? W_ - 2 : ws);
        const float hr = h - (float)hs;
        const float wr = w - (float)ws;
        const float vz = valid ? 1.0f : 0.0f;
        float4 wt;
        wt.x = (1.0f - hr) * (1.0f - wr) * vz;
        wt.y = (1.0f - hr) * wr * vz;
        wt.z = hr * (1.0f - wr) * vz;
        wt.w = hr * wr * vz;
        swt[s]  = wt;
        soff[s] = b * sB + hs * sH + ws * sW;
    }
    __syncthreads();
    const int lane = tid & 63;
    const int wv   = tid >> 6;
    for (int chunk = 0; chunk < C_ / 64; ++chunk) {
        const int cbase = (chunk * 64 + lane) * sC;
        #pragma unroll 4
        for (int k = 0; k < 16; ++k) {
            const int s = wv * 16 + k;
            const float4 wt = swt[s];
            const int off = soff[s] + cbase;
            sval[lane * 65 + s] = ft[off]            * wt.x + ft[off + sW]      * wt.y +
                                  ft[off + sH]       * wt.z + ft[off + sH + sW] * wt.w;
        }
        __syncthreads();
        const int out_base = n * (C_ * 49) + chunk * (64 * 49);
        #pragma unroll
        for (int r = 0; r < 13; ++r) {
            const int o = r * 256 + tid;
            if (o < 64 * 49) {
                const int c  = o / 49;
                const int ji = o - c * 49;
                const int jj = ji / 7;
                const int s  = ji + jj;
                const float* sv = &sval[c * 65 + s];
                out[out_base + o] = 0.25f * (sv[0] + sv[1] + sv[8] + sv[9]);
            }
        }
        __syncthreads();
    }
}

extern "C" void kernel_launch(void* const* d_in, const int* in_sizes, int n_in,
                              void* d_out, int out_size, void* d_ws, size_t ws_size,
                              hipStream_t stream) {
    const float* features = (const float*)d_in[0];
    const float* rois     = (const float*)d_in[1];
    float* out            = (float*)d_out;

    const size_t need = (size_t)B_ * C_ * H_ * W_ * sizeof(__hip_bfloat16);
    if (ws_size >= need) {
        __hip_bfloat16* ftb = (__hip_bfloat16*)d_ws;
        dim3 g((H_ * W_ + 31) / 32, (C_ + 31) / 32, B_);
        dim3 b(32, 8, 1);
        transcvt_k<<<g, b, 0, stream>>>(features, ftb);
        roi_avg_v6<<<N_, 256, 0, stream>>>(ftb, rois, out);
    } else {
        roi_avg_generic<<<N_, 256, 0, stream>>>(features, rois, out,
                                                C_ * H_ * W_, W_, 1, H_ * W_);
    }
}

// Round 5
// 227.840 us; speedup vs baseline: 1.0273x; 1.0273x over previous
//
#include <hip/hip_runtime.h>
#include <hip/hip_bf16.h>

#define B_ 2
#define C_ 512
#define H_ 50
#define W_ 75
#define N_ 2000
#define SS (1.0f/16.0f)

#define SB (H_ * W_ * C_)   // batch stride (elements), NHWC
#define SH (W_ * C_)        // row stride
#define SW (C_)             // col stride

// lgkm-only barrier: orders LDS traffic across the workgroup WITHOUT
// draining global loads/stores.
#define BAR_LGKM() asm volatile("s_waitcnt lgkmcnt(0)\n\ts_barrier" ::: "memory")

__device__ __forceinline__ float bf2f(unsigned short u) {
    union { unsigned i; float f; } c; c.i = (unsigned)u << 16; return c.f;
}

// fused transpose+convert: (B,C,H,W) fp32 -> (B,H,W,C) bf16
__global__ __launch_bounds__(256) void transcvt_k(const float* __restrict__ in,
                                                  __hip_bfloat16* __restrict__ out) {
    __shared__ float tile[32][33];
    const int b   = blockIdx.z;
    const int hw0 = blockIdx.x * 32;
    const int c0  = blockIdx.y * 32;
    const int tx  = threadIdx.x;
    const int ty  = threadIdx.y;
    #pragma unroll
    for (int r = 0; r < 32; r += 8) {
        int c  = c0 + ty + r;
        int hw = hw0 + tx;
        if (c < C_ && hw < H_ * W_)
            tile[ty + r][tx] = in[(b * C_ + c) * (H_ * W_) + hw];
    }
    __syncthreads();
    #pragma unroll
    for (int r = 0; r < 32; r += 8) {
        int hw = hw0 + ty + r;
        int c  = c0 + tx;
        if (hw < H_ * W_ && c < C_)
            out[(b * (H_ * W_) + hw) * C_ + c] = __float2bfloat16(tile[tx][ty + r]);
    }
}

// v7: one block = one (roi, channel-chunk). chunk = blockIdx.x % 8 so the
// XCD round-robin dispatch pins each XCD to ONE 960KB channel slice of the
// feature map -> slice stays L2-resident (previously ~256 resident blocks
// per XCD spanned all 8 chunks = 7.7MB > 4MB L2 -> chronic thrash, gather
// served from L3 at random-access rates = the ~100us wall that was
// insensitive to occupancy/barriers/store policy in v4/v5/v6).
// Per block: setup (64 threads) -> gather 64 samples x 64ch -> reduce.
// sval channel-major stride 65: write 2-way banks (free), read stride-1.
__global__ __launch_bounds__(256) void roi_avg_v7(
    const __hip_bfloat16* __restrict__ ftb, const float* __restrict__ rois,
    float* __restrict__ out)
{
    __shared__ float  sval[64 * 65];   // [chan-in-chunk][sample], stride 65
    __shared__ float4 swt[64];
    __shared__ int    soff[64];

    const int bid   = blockIdx.x;
    const int chunk = bid & 7;         // pinned to XCD by dispatch round-robin
    const int n     = bid >> 3;
    const int tid   = threadIdx.x;

    if (tid < 64) {
        const int s = tid;
        const int j = s >> 3;
        const int i = s & 7;
        const float bfv = rois[n * 5 + 0];
        const float x1 = rois[n * 5 + 1] * SS;
        const float y1 = rois[n * 5 + 2] * SS;
        const float x2 = rois[n * 5 + 3] * SS;
        const float y2 = rois[n * 5 + 4] * SS;
        const int b = (int)bfv;
        const float roi_w = fmaxf(x2 - x1 + 1.0f, 0.0f);
        const float roi_h = fmaxf(y2 - y1 + 1.0f, 0.0f);
        const float h = y1 + (float)j * (roi_h / 7.0f);
        const float w = x1 + (float)i * (roi_w / 7.0f);
        const bool valid = (h >= 0.0f) && (h < (float)H_) &&
                           (w >= 0.0f) && (w < (float)W_);
        int hs = (int)floorf(h); hs = hs < 0 ? 0 : (hs > H_ - 2 ? H_ - 2 : hs);
        int ws = (int)floorf(w); ws = ws < 0 ? 0 : (ws > W_ - 2 ? W_ - 2 : ws);
        const float hr = h - (float)hs;
        const float wr = w - (float)ws;
        const float vz = valid ? 1.0f : 0.0f;
        float4 wt;
        wt.x = (1.0f - hr) * (1.0f - wr) * vz;
        wt.y = (1.0f - hr) * wr * vz;
        wt.z = hr * (1.0f - wr) * vz;
        wt.w = hr * wr * vz;
        swt[s]  = wt;
        soff[s] = b * SB + hs * SH + ws * SW;
    }
    BAR_LGKM();

    const unsigned short* const ft = (const unsigned short*)ftb;
    const int lane = tid & 63;
    const int wv   = tid >> 6;
    const int q    = lane >> 4;        // sample sub-index 0..3
    const int l    = lane & 15;        // channel-quad index
    const int cl   = l * 4;            // channel within chunk (0..63)

    const int cbase = chunk * 64 + cl;
    #pragma unroll
    for (int k = 0; k < 4; ++k) {
        const int s = wv * 16 + k * 4 + q;
        const float4 wt = swt[s];
        const unsigned short* p = ft + soff[s] + cbase;
        const ushort4 a = *(const ushort4*)(p);
        const ushort4 bq = *(const ushort4*)(p + SW);
        const ushort4 c = *(const ushort4*)(p + SH);
        const ushort4 d = *(const ushort4*)(p + SH + SW);
        const float v0 = bf2f(a.x) * wt.x + bf2f(bq.x) * wt.y + bf2f(c.x) * wt.z + bf2f(d.x) * wt.w;
        const float v1 = bf2f(a.y) * wt.x + bf2f(bq.y) * wt.y + bf2f(c.y) * wt.z + bf2f(d.y) * wt.w;
        const float v2 = bf2f(a.z) * wt.x + bf2f(bq.z) * wt.y + bf2f(c.z) * wt.z + bf2f(d.z) * wt.w;
        const float v3 = bf2f(a.w) * wt.x + bf2f(bq.w) * wt.y + bf2f(c.w) * wt.z + bf2f(d.w) * wt.w;
        // channel-major scatter; stride 65 dwords -> ds_write2_b32 pairs
        sval[(cl + 0) * 65 + s] = v0;
        sval[(cl + 1) * 65 + s] = v1;
        sval[(cl + 2) * 65 + s] = v2;
        sval[(cl + 3) * 65 + s] = v3;
    }
    BAR_LGKM();

    const int out_base = n * (C_ * 49) + chunk * (64 * 49);
    #pragma unroll
    for (int r = 0; r < 13; ++r) {
        const int o = r * 256 + tid;
        if (o < 64 * 49) {
            const int c  = o / 49;       // chan-in-chunk, ~fixed across a wave
            const int ji = o - c * 49;
            const int jj = ji / 7;
            const int s  = ji + jj;      // j*8+i == (j*7+i)+j
            const float* sv = &sval[c * 65 + s];
            // (sv[0],sv[1]) and (sv[8],sv[9]) -> ds_read2_b32, s-stride-1
            const float v = 0.25f * (sv[0] + sv[1] + sv[8] + sv[9]);
            __builtin_nontemporal_store(v, &out[out_base + o]);  // stream past L2
        }
    }
}

// Fallback: fp32 native-layout version (only if ws too small)
__global__ __launch_bounds__(256) void roi_avg_generic(
    const float* __restrict__ ft, const float* __restrict__ rois,
    float* __restrict__ out, int sB, int sH, int sW, int sC)
{
    __shared__ float  sval[64 * 65];
    __shared__ float4 swt[64];
    __shared__ int    soff[64];
    const int n   = blockIdx.x;
    const int tid = threadIdx.x;
    if (tid < 64) {
        const int s = tid;
        const int j = s >> 3;
        const int i = s & 7;
        const float bfv = rois[n * 5 + 0];
        const float x1 = rois[n * 5 + 1] * SS;
        const float y1 = rois[n * 5 + 2] * SS;
        const float x2 = rois[n * 5 + 3] * SS;
        const float y2 = rois[n * 5 + 4] * SS;
        const int b = (int)bfv;
        const float roi_w = fmaxf(x2 - x1 + 1.0f, 0.0f);
        const float roi_h = fmaxf(y2 - y1 + 1.0f, 0.0f);
        const float h = y1 + (float)j * (roi_h / 7.0f);
        const float w = x1 + (float)i * (roi_w / 7.0f);
        const bool valid = (h >= 0.0f) && (h < (float)H_) && (w >= 0.0f) && (w < (float)W_);
        int hs = (int)floorf(h); hs = hs < 0 ? 0 : (hs > H_ - 2 ? H_ - 2 : hs);
        int ws = (int)floorf(w); ws = ws < 0 ? 0 : (ws > W_ - 2 ? W_ - 2 : ws);
        const float hr = h - (float)hs;
        const float wr = w - (float)ws;
        const float vz = valid ? 1.0f : 0.0f;
        float4 wt;
        wt.x = (1.0f - hr) * (1.0f - wr) * vz;
        wt.y = (1.0f - hr) * wr * vz;
        wt.z = hr * (1.0f - wr) * vz;
        wt.w = hr * wr * vz;
        swt[s]  = wt;
        soff[s] = b * sB + hs * sH + ws * sW;
    }
    __syncthreads();
    const int lane = tid & 63;
    const int wv   = tid >> 6;
    for (int chunk = 0; chunk < C_ / 64; ++chunk) {
        const int cbase = (chunk * 64 + lane) * sC;
        #pragma unroll 4
        for (int k = 0; k < 16; ++k) {
            const int s = wv * 16 + k;
            const float4 wt = swt[s];
            const int off = soff[s] + cbase;
            sval[lane * 65 + s] = ft[off]            * wt.x + ft[off + sW]      * wt.y +
                                  ft[off + sH]       * wt.z + ft[off + sH + sW] * wt.w;
        }
        __syncthreads();
        const int out_base = n * (C_ * 49) + chunk * (64 * 49);
        #pragma unroll
        for (int r = 0; r < 13; ++r) {
            const int o = r * 256 + tid;
            if (o < 64 * 49) {
                const int c  = o / 49;
                const int ji = o - c * 49;
                const int jj = ji / 7;
                const int s  = ji + jj;
                const float* sv = &sval[c * 65 + s];
                out[out_base + o] = 0.25f * (sv[0] + sv[1] + sv[8] + sv[9]);
            }
        }
        __syncthreads();
    }
}

extern "C" void kernel_launch(void* const* d_in, const int* in_sizes, int n_in,
                              void* d_out, int out_size, void* d_ws, size_t ws_size,
                              hipStream_t stream) {
    const float* features = (const float*)d_in[0];
    const float* rois     = (const float*)d_in[1];
    float* out            = (float*)d_out;

    const size_t need = (size_t)B_ * C_ * H_ * W_ * sizeof(__hip_bfloat16);
    if (ws_size >= need) {
        __hip_bfloat16* ftb = (__hip_bfloat16*)d_ws;
        dim3 g((H_ * W_ + 31) / 32, (C_ + 31) / 32, B_);
        dim3 b(32, 8, 1);
        transcvt_k<<<g, b, 0, stream>>>(features, ftb);
        roi_avg_v7<<<N_ * 8, 256, 0, stream>>>(ftb, rois, out);
    } else {
        roi_avg_generic<<<N_, 256, 0, stream>>>(features, rois, out,
                                                C_ * H_ * W_, W_, 1, H_ * W_);
    }
}

// Round 6
// 223.218 us; speedup vs baseline: 1.0485x; 1.0207x over previous
//
#include <hip/hip_runtime.h>
#include <hip/hip_bf16.h>

#define B_ 2
#define C_ 512
#define H_ 50
#define W_ 75
#define N_ 2000
#define SS (1.0f/16.0f)

#define SB (H_ * W_ * C_)   // batch stride (elements), NHWC
#define SH (W_ * C_)        // row stride
#define SW (C_)             // col stride

// lgkm-only barrier: orders LDS traffic across the workgroup WITHOUT
// draining global loads/stores.
#define BAR_LGKM() asm volatile("s_waitcnt lgkmcnt(0)\n\ts_barrier" ::: "memory")

typedef unsigned short ushortx8 __attribute__((ext_vector_type(8)));

__device__ __forceinline__ float bf2f(unsigned short u) {
    union { unsigned i; float f; } c; c.i = (unsigned)u << 16; return c.f;
}

// fused transpose+convert: (B,C,H,W) fp32 -> (B,H,W,C) bf16
// v2: 64-channel tile, packed bf16x2 stores (4B/lane, was 2B scalar).
__global__ __launch_bounds__(256) void transcvt_k2(const float* __restrict__ in,
                                                   __hip_bfloat16* __restrict__ out) {
    __shared__ float tile[64][33];
    const int b   = blockIdx.z;
    const int hw0 = blockIdx.x * 32;
    const int c0  = blockIdx.y * 64;
    const int tx  = threadIdx.x;   // 0..31
    const int ty  = threadIdx.y;   // 0..7
    const int hw  = hw0 + tx;
    if (hw < H_ * W_) {
        #pragma unroll
        for (int rr = 0; rr < 8; ++rr) {
            const int c = c0 + rr * 8 + ty;
            tile[rr * 8 + ty][tx] = in[(b * C_ + c) * (H_ * W_) + hw];
        }
    }
    __syncthreads();
    const int c2 = 2 * tx;
    #pragma unroll
    for (int rr = 0; rr < 4; ++rr) {
        const int hwl = rr * 8 + ty;
        const int hww = hw0 + hwl;
        if (hww < H_ * W_) {
            const __hip_bfloat16 lo = __float2bfloat16(tile[c2][hwl]);
            const __hip_bfloat16 hi = __float2bfloat16(tile[c2 + 1][hwl]);
            union { unsigned short u[2]; unsigned v; } pk;
            pk.u[0] = *(const unsigned short*)&lo;
            pk.u[1] = *(const unsigned short*)&hi;
            *(unsigned*)&out[((size_t)b * (H_ * W_) + hww) * C_ + c0 + c2] = pk.v;
        }
    }
}

// v8: v7 structure (one block = one (roi, chunk); chunk = bid&7 pins each
// XCD to one 960KB channel slice via dispatch round-robin) +
//  - 16B ushort8 gather loads: 8 channels/lane, 8 lanes/sample -> global
//    load instruction count halved (16 -> 8 per thread), half the vmcnt
//    wait events.
//  - NT output stores, lgkm-only barriers (kept from v6/v7).
// sval channel-major stride 65: write banks 2-way (free: 8*(lane&7)+
// (lane>>3) covers each bank exactly 2x), read s-stride-1 conflict-free.
__global__ __launch_bounds__(256) void roi_avg_v8(
    const __hip_bfloat16* __restrict__ ftb, const float* __restrict__ rois,
    float* __restrict__ out)
{
    __shared__ float  sval[64 * 65];   // [chan-in-chunk][sample], stride 65
    __shared__ float4 swt[64];
    __shared__ int    soff[64];

    const int bid   = blockIdx.x;
    const int chunk = bid & 7;         // pinned to XCD by dispatch round-robin
    const int n     = bid >> 3;
    const int tid   = threadIdx.x;

    if (tid < 64) {
        const int s = tid;
        const int j = s >> 3;
        const int i = s & 7;
        const float bfv = rois[n * 5 + 0];
        const float x1 = rois[n * 5 + 1] * SS;
        const float y1 = rois[n * 5 + 2] * SS;
        const float x2 = rois[n * 5 + 3] * SS;
        const float y2 = rois[n * 5 + 4] * SS;
        const int b = (int)bfv;
        const float roi_w = fmaxf(x2 - x1 + 1.0f, 0.0f);
        const float roi_h = fmaxf(y2 - y1 + 1.0f, 0.0f);
        const float h = y1 + (float)j * (roi_h / 7.0f);
        const float w = x1 + (float)i * (roi_w / 7.0f);
        const bool valid = (h >= 0.0f) && (h < (float)H_) &&
                           (w >= 0.0f) && (w < (float)W_);
        int hs = (int)floorf(h); hs = hs < 0 ? 0 : (hs > H_ - 2 ? H_ - 2 : hs);
        int ws = (int)floorf(w); ws = ws < 0 ? 0 : (ws > W_ - 2 ? W_ - 2 : ws);
        const float hr = h - (float)hs;
        const float wr = w - (float)ws;
        const float vz = valid ? 1.0f : 0.0f;
        float4 wt;
        wt.x = (1.0f - hr) * (1.0f - wr) * vz;
        wt.y = (1.0f - hr) * wr * vz;
        wt.z = hr * (1.0f - wr) * vz;
        wt.w = hr * wr * vz;
        swt[s]  = wt;
        soff[s] = b * SB + hs * SH + ws * SW;
    }
    BAR_LGKM();

    const unsigned short* const ft = (const unsigned short*)ftb;
    const int lane = tid & 63;
    const int wv   = tid >> 6;
    const int q    = lane >> 3;        // sample sub-index 0..7
    const int l    = lane & 7;         // channel-octet index
    const int cl   = l * 8;            // channel within chunk (0..56)

    const int cbase = chunk * 64 + cl;
    #pragma unroll
    for (int k = 0; k < 2; ++k) {
        const int s = wv * 16 + k * 8 + q;
        const float4 wt = swt[s];
        const unsigned short* p = ft + soff[s] + cbase;   // 16B-aligned
        const ushortx8 a  = *(const ushortx8*)(p);
        const ushortx8 bq = *(const ushortx8*)(p + SW);
        const ushortx8 c  = *(const ushortx8*)(p + SH);
        const ushortx8 d  = *(const ushortx8*)(p + SH + SW);
        #pragma unroll
        for (int e = 0; e < 8; ++e) {
            // channel-major scatter; e-stride 65 dwords -> ds_write2_b32 pairs
            sval[(cl + e) * 65 + s] =
                bf2f(a[e])  * wt.x + bf2f(bq[e]) * wt.y +
                bf2f(c[e])  * wt.z + bf2f(d[e])  * wt.w;
        }
    }
    BAR_LGKM();

    const int out_base = n * (C_ * 49) + chunk * (64 * 49);
    #pragma unroll
    for (int r = 0; r < 13; ++r) {
        const int o = r * 256 + tid;
        if (o < 64 * 49) {
            const int c  = o / 49;       // chan-in-chunk, ~fixed across a wave
            const int ji = o - c * 49;
            const int jj = ji / 7;
            const int s  = ji + jj;      // j*8+i == (j*7+i)+j
            const float* sv = &sval[c * 65 + s];
            // (sv[0],sv[1]) and (sv[8],sv[9]) -> ds_read2_b32, s-stride-1
            const float v = 0.25f * (sv[0] + sv[1] + sv[8] + sv[9]);
            __builtin_nontemporal_store(v, &out[out_base + o]);  // stream past L2
        }
    }
}

// Fallback: fp32 native-layout version (only if ws too small)
__global__ __launch_bounds__(256) void roi_avg_generic(
    const float* __restrict__ ft, const float* __restrict__ rois,
    float* __restrict__ out, int sB, int sH, int sW, int sC)
{
    __shared__ float  sval[64 * 65];
    __shared__ float4 swt[64];
    __shared__ int    soff[64];
    const int n   = blockIdx.x;
    const int tid = threadIdx.x;
    if (tid < 64) {
        const int s = tid;
        const int j = s >> 3;
        const int i = s & 7;
        const float bfv = rois[n * 5 + 0];
        const float x1 = rois[n * 5 + 1] * SS;
        const float y1 = rois[n * 5 + 2] * SS;
        const float x2 = rois[n * 5 + 3] * SS;
        const float y2 = rois[n * 5 + 4] * SS;
        const int b = (int)bfv;
        const float roi_w = fmaxf(x2 - x1 + 1.0f, 0.0f);
        const float roi_h = fmaxf(y2 - y1 + 1.0f, 0.0f);
        const float h = y1 + (float)j * (roi_h / 7.0f);
        const float w = x1 + (float)i * (roi_w / 7.0f);
        const bool valid = (h >= 0.0f) && (h < (float)H_) && (w >= 0.0f) && (w < (float)W_);
        int hs = (int)floorf(h); hs = hs < 0 ? 0 : (hs > H_ - 2 ? H_ - 2 : hs);
        int ws = (int)floorf(w); ws = ws < 0 ? 0 : (ws > W_ - 2 ? W_ - 2 : ws);
        const float hr = h - (float)hs;
        const float wr = w - (float)ws;
        const float vz = valid ? 1.0f : 0.0f;
        float4 wt;
        wt.x = (1.0f - hr) * (1.0f - wr) * vz;
        wt.y = (1.0f - hr) * wr * vz;
        wt.z = hr * (1.0f - wr) * vz;
        wt.w = hr * wr * vz;
        swt[s]  = wt;
        soff[s] = b * sB + hs * sH + ws * sW;
    }
    __syncthreads();
    const int lane = tid & 63;
    const int wv   = tid >> 6;
    for (int chunk = 0; chunk < C_ / 64; ++chunk) {
        const int cbase = (chunk * 64 + lane) * sC;
        #pragma unroll 4
        for (int k = 0; k < 16; ++k) {
            const int s = wv * 16 + k;
            const float4 wt = swt[s];
            const int off = soff[s] + cbase;
            sval[lane * 65 + s] = ft[off]            * wt.x + ft[off + sW]      * wt.y +
                                  ft[off + sH]       * wt.z + ft[off + sH + sW] * wt.w;
        }
        __syncthreads();
        const int out_base = n * (C_ * 49) + chunk * (64 * 49);
        #pragma unroll
        for (int r = 0; r < 13; ++r) {
            const int o = r * 256 + tid;
            if (o < 64 * 49) {
                const int c  = o / 49;
                const int ji = o - c * 49;
                const int jj = ji / 7;
                const int s  = ji + jj;
                const float* sv = &sval[c * 65 + s];
                out[out_base + o] = 0.25f * (sv[0] + sv[1] + sv[8] + sv[9]);
            }
        }
        __syncthreads();
    }
}

extern "C" void kernel_launch(void* const* d_in, const int* in_sizes, int n_in,
                              void* d_out, int out_size, void* d_ws, size_t ws_size,
                              hipStream_t stream) {
    const float* features = (const float*)d_in[0];
    const float* rois     = (const float*)d_in[1];
    float* out            = (float*)d_out;

    const size_t need = (size_t)B_ * C_ * H_ * W_ * sizeof(__hip_bfloat16);
    if (ws_size >= need) {
        __hip_bfloat16* ftb = (__hip_bfloat16*)d_ws;
        dim3 g((H_ * W_ + 31) / 32, C_ / 64, B_);
        dim3 b(32, 8, 1);
        transcvt_k2<<<g, b, 0, stream>>>(features, ftb);
        roi_avg_v8<<<N_ * 8, 256, 0, stream>>>(ftb, rois, out);
    } else {
        roi_avg_generic<<<N_, 256, 0, stream>>>(features, rois, out,
                                                C_ * H_ * W_, W_, 1, H_ * W_);
    }
}